// Round 1
// 1338.419 us; speedup vs baseline: 1.0674x; 1.0674x over previous
//
#include <hip/hip_runtime.h>
#include <math.h>

// Problem shape (fixed by reference): B=256, F_IN=1024, F_OUT=1024
#define BATCH 256
#define FIN   1024
#define FOUT  1024

typedef float f4 __attribute__((ext_vector_type(4)));

__device__ __forceinline__ float softplus_f(float x) {
    // numerically stable: max(x,0) + log1p(exp(-|x|))
    return fmaxf(x, 0.0f) + log1pf(expf(-fabsf(x)));
}

__device__ __forceinline__ f4 softplus_v(f4 r) {
    f4 s;
    s.x = softplus_f(r.x);
    s.y = softplus_f(r.y);
    s.z = softplus_f(r.z);
    s.w = softplus_f(r.w);
    return s;
}

__device__ __forceinline__ float dot_acc(f4 xv, f4 se, f4 ev, f4 me, float acc) {
    // acc += x * (mu + softplus(rho) * eps)
    acc = fmaf(xv.x, fmaf(se.x, ev.x, me.x), acc);
    acc = fmaf(xv.y, fmaf(se.y, ev.y, me.y), acc);
    acc = fmaf(xv.z, fmaf(se.z, ev.z, me.z), acc);
    acc = fmaf(xv.w, fmaf(se.w, ev.w, me.w), acc);
    return acc;
}

// Fused kernel, NO workspace use (theory: timed region is dominated by the
// harness re-poisoning the 4 GiB workspace; drop the dependency entirely).
//
// Decomposition: each wave owns one output column o and FOUR batches
// (b0..b0+3). softplus(weight_rho[o,:]) is computed once per wave and
// reused across the 4 batches (4x fewer transcendentals and 4x less
// mu/rho L2/L3 traffic than the one-(b,o)-per-wave layout).
//
// grid: 64 b-groups x 256 o-groups = 16384 blocks; 4 waves/block, wave w
// handles o = (blockIdx%256)*4 + w. Consecutive waves read consecutive
// 4 KB eps_w rows -> 16 KB contiguous per b-plane per block.
__global__ void __launch_bounds__(256) bayes_linear_fused(
    const float* __restrict__ x,       // (B, FIN)
    const float* __restrict__ mu,      // (FOUT, FIN)
    const float* __restrict__ rho,     // (FOUT, FIN)
    const float* __restrict__ bmu,     // (FOUT)
    const float* __restrict__ brho,    // (FOUT)
    const float* __restrict__ eps_w,   // (B, FOUT, FIN)
    const float* __restrict__ eps_b,   // (B, FOUT)
    float* __restrict__ out)           // (B, FOUT)
{
    const int warp = threadIdx.x >> 6;
    const int lane = threadIdx.x & 63;
    const int bg   = blockIdx.x >> 8;                  // 64 groups of 4 batches
    const int o    = ((blockIdx.x & 255) << 2) | warp; // output column
    const int b0   = bg << 2;                          // first batch of group

    const float* mur = mu  + (size_t)o * FIN;
    const float* rhr = rho + (size_t)o * FIN;
    const float* xr  = x   + (size_t)b0 * FIN;
    const float* er  = eps_w + ((size_t)b0 * FOUT + o) * FIN;
    const size_t BSTRIDE = (size_t)FOUT * FIN;         // eps_w batch stride

    float a0 = 0.0f, a1 = 0.0f, a2 = 0.0f, a3 = 0.0f;

#pragma unroll
    for (int c = 0; c < 4; ++c) {
        const int idx = c * 256 + lane * 4;

        f4 me = *(const f4*)(mur + idx);               // L2/L3-resident
        f4 se = softplus_v(*(const f4*)(rhr + idx));   // computed once, used 4x

        f4 x0 = *(const f4*)(xr + idx);                // L1/L2-resident
        f4 x1 = *(const f4*)(xr + FIN + idx);
        f4 x2 = *(const f4*)(xr + 2 * FIN + idx);
        f4 x3 = *(const f4*)(xr + 3 * FIN + idx);

        // HBM stream, zero reuse -> non-temporal
        f4 e0 = __builtin_nontemporal_load((const f4*)(er + idx));
        f4 e1 = __builtin_nontemporal_load((const f4*)(er + BSTRIDE + idx));
        f4 e2 = __builtin_nontemporal_load((const f4*)(er + 2 * BSTRIDE + idx));
        f4 e3 = __builtin_nontemporal_load((const f4*)(er + 3 * BSTRIDE + idx));

        a0 = dot_acc(x0, se, e0, me, a0);
        a1 = dot_acc(x1, se, e1, me, a1);
        a2 = dot_acc(x2, se, e2, me, a2);
        a3 = dot_acc(x3, se, e3, me, a3);
    }

    // wave-wide butterfly reduction (64 lanes) for all 4 accumulators
#pragma unroll
    for (int off = 32; off > 0; off >>= 1) {
        a0 += __shfl_xor(a0, off, 64);
        a1 += __shfl_xor(a1, off, 64);
        a2 += __shfl_xor(a2, off, 64);
        a3 += __shfl_xor(a3, off, 64);
    }

    if (lane == 0) {
        const float bm = bmu[o];
        const float sb = softplus_f(brho[o]);
        out[(size_t)(b0 + 0) * FOUT + o] = a0 + bm + sb * eps_b[(size_t)(b0 + 0) * FOUT + o];
        out[(size_t)(b0 + 1) * FOUT + o] = a1 + bm + sb * eps_b[(size_t)(b0 + 1) * FOUT + o];
        out[(size_t)(b0 + 2) * FOUT + o] = a2 + bm + sb * eps_b[(size_t)(b0 + 2) * FOUT + o];
        out[(size_t)(b0 + 3) * FOUT + o] = a3 + bm + sb * eps_b[(size_t)(b0 + 3) * FOUT + o];
    }
}

extern "C" void kernel_launch(void* const* d_in, const int* in_sizes, int n_in,
                              void* d_out, int out_size, void* d_ws, size_t ws_size,
                              hipStream_t stream) {
    const float* x     = (const float*)d_in[0];
    const float* wmu   = (const float*)d_in[1];
    const float* wrho  = (const float*)d_in[2];
    const float* bmu   = (const float*)d_in[3];
    const float* brho  = (const float*)d_in[4];
    const float* eps_w = (const float*)d_in[5];
    const float* eps_b = (const float*)d_in[6];
    float* out = (float*)d_out;

    (void)d_ws; (void)ws_size; // deliberately unused: avoid workspace re-poison cost

    // 64 b-groups * 256 o-groups; 4 waves (4 consecutive o) per block
    const int blocks = (BATCH / 4) * (FOUT / 4);
    bayes_linear_fused<<<blocks, 256, 0, stream>>>(
        x, wmu, wrho, bmu, brho, eps_w, eps_b, out);
}